// Round 1
// 485.833 us; speedup vs baseline: 1.0206x; 1.0206x over previous
//
#include <hip/hip_runtime.h>

typedef __bf16 bf16x8 __attribute__((ext_vector_type(8)));
typedef float  f32x4  __attribute__((ext_vector_type(4)));
typedef unsigned short us8 __attribute__((ext_vector_type(8)));
typedef unsigned short us4 __attribute__((ext_vector_type(4)));

__device__ __forceinline__ float bf2f(unsigned short u) {
    return __builtin_bit_cast(float, (unsigned int)u << 16);
}
__device__ __forceinline__ unsigned short f2bf(float f) {
    return __builtin_bit_cast(unsigned short, (__bf16)f);
}

// ---------------- fused weight prep: 4x f32 W[k][n] -> transposed bf16 hi/lo planes ----------------
// wt layout per matrix m: [m*32768 .. ]: hiT[128*128], loT[128*128]
__global__ void prep_w4(const float* __restrict__ W0, const float* __restrict__ W1,
                        const float* __restrict__ W2, const float* __restrict__ W3,
                        unsigned short* __restrict__ wt) {
    int i = blockIdx.x * 256 + threadIdx.x;    // 0..65535
    int m = i >> 14, r = i & 16383;
    const float* W = (m == 0) ? W0 : (m == 1) ? W1 : (m == 2) ? W2 : W3;
    float f = W[r];
    int k = r >> 7, n = r & 127;
    __bf16 h = (__bf16)f;
    __bf16 l = (__bf16)(f - (float)h);
    unsigned short* base = wt + m * 32768;
    base[n * 128 + k]         = __builtin_bit_cast(unsigned short, h);
    base[16384 + n * 128 + k] = __builtin_bit_cast(unsigned short, l);
}

// ---------------- f32 -> bf16 plane (x conversion) ----------------
__global__ void to_bf16(const float* __restrict__ in, unsigned short* __restrict__ out, int n4) {
    int i = blockIdx.x * 256 + threadIdx.x;
    if (i < n4) {
        f32x4 v = ((const f32x4*)in)[i];
        us4 o;
        o[0] = f2bf(v[0]); o[1] = f2bf(v[1]); o[2] = f2bf(v[2]); o[3] = f2bf(v[3]);
        ((us4*)out)[i] = o;
    }
}

// ---------------- CSR build ----------------
__global__ void count_deg(const int* __restrict__ dst, int* __restrict__ cnt, int E) {
    int e = blockIdx.x * 256 + threadIdx.x;
    if (e < E) atomicAdd(&cnt[dst[e]], 1);
}

__global__ void scanA(const int* __restrict__ cnt, int* __restrict__ rowptr,
                      int* __restrict__ bsum, int N) {
    __shared__ int s[1024];
    int t = threadIdx.x;
    int idx = blockIdx.x * 1024 + t;
    int v = (idx < N) ? cnt[idx] : 0;
    int sum = v;
    s[t] = sum;
    __syncthreads();
    for (int o = 1; o < 1024; o <<= 1) {
        int u = (t >= o) ? s[t - o] : 0;
        __syncthreads();
        sum += u;
        s[t] = sum;
        __syncthreads();
    }
    if (idx < N) rowptr[idx] = sum - v;
    if (t == 1023) bsum[blockIdx.x] = sum;
}

__global__ void scanB(int* __restrict__ bsum, int nb) {
    __shared__ int s[128];
    int t = threadIdx.x;
    int v = (t < nb) ? bsum[t] : 0;
    int sum = v;
    s[t] = sum;
    __syncthreads();
    for (int o = 1; o < 128; o <<= 1) {
        int u = (t >= o) ? s[t - o] : 0;
        __syncthreads();
        sum += u;
        s[t] = sum;
        __syncthreads();
    }
    if (t < nb) bsum[t] = sum - v;
}

// finalize: absolute rowptr, fill cursor, dinv, selfw = dinv^2
__global__ void scanC(int* __restrict__ rowptr, const int* __restrict__ bsum,
                      int* __restrict__ cnt_cursor, float* __restrict__ dinv,
                      float* __restrict__ selfw, int N, int E) {
    int i = blockIdx.x * 256 + threadIdx.x;
    if (i < N) {
        int c = cnt_cursor[i];
        int a = rowptr[i] + bsum[i >> 10];
        rowptr[i] = a;
        cnt_cursor[i] = a;
        float dv = rsqrtf((float)(c + 1));
        dinv[i] = dv;
        selfw[i] = dv * dv;
    }
    if (i == 0) rowptr[N] = E;
}

// fill edge records (4B: src only), dst-range-partitioned so each range's
// scattered writes stay within ONE XCD's L2 and merge into full lines.
// range = blockIdx & 7 tracks the round-robin blockIdx->XCD mapping.
__global__ void fill_csr(const int* __restrict__ src, const int* __restrict__ dst,
                         int* __restrict__ cursor, int* __restrict__ epack,
                         int E, int N) {
    const int range = blockIdx.x & 7;
    const int e = (blockIdx.x >> 3) * 256 + threadIdx.x;
    const int RANGE = (N + 7) >> 3;
    const int lo = range * RANGE;
    const int hi = (lo + RANGE < N) ? lo + RANGE : N;
    if (e < E) {
        int d = dst[e];
        if (d >= lo && d < hi) {
            int p = atomicAdd(&cursor[d], 1);
            epack[p] = src[e];
        }
    }
}

// ---------------- GEMM: C[M,128] = A[M,128](bf16) @ W[128,128](split hi/lo) ----------------
// mode 0: no bias, write Cb (bf16); mode 1: +bias, PReLU, write Cb; mode 2: +bias, write Cf (f32)
__global__ __launch_bounds__(256) void gemm128s(
    const unsigned short* __restrict__ Ahi, const unsigned short* __restrict__ WhiT,
    const unsigned short* __restrict__ WloT, const float* __restrict__ bias,
    const float* __restrict__ prelu_a, float* __restrict__ Cf,
    unsigned short* __restrict__ Cb, int M, int mode)
{
    __shared__ unsigned short sHi[128 * 136];
    __shared__ unsigned short sLo[128 * 136];
    const int tid = threadIdx.x;

    for (int i = tid; i < 2048; i += 256) {
        int row = i >> 4, seg = i & 15;
        *(us8*)(&sHi[row * 136 + seg * 8]) = *(const us8*)(WhiT + row * 128 + seg * 8);
        *(us8*)(&sLo[row * 136 + seg * 8]) = *(const us8*)(WloT + row * 128 + seg * 8);
    }
    __syncthreads();

    const int lane = tid & 63;
    const int wave = tid >> 6;
    const int lc   = lane & 15;
    const int quad = lane >> 4;
    const int rowBlock = blockIdx.x * 128 + wave * 32;

    f32x4 acc[2][8];
    const f32x4 z4 = {0.f, 0.f, 0.f, 0.f};
#pragma unroll
    for (int rs = 0; rs < 2; ++rs)
#pragma unroll
        for (int t = 0; t < 8; ++t) acc[rs][t] = z4;

#pragma unroll
    for (int ks = 0; ks < 4; ++ks) {
        const int kf = ks * 32 + quad * 8;
        bf16x8 a[2];
#pragma unroll
        for (int rs = 0; rs < 2; ++rs) {
            int r = rowBlock + rs * 16 + lc;
            if (r > M - 1) r = M - 1;
            a[rs] = __builtin_bit_cast(bf16x8, *(const us8*)(Ahi + (size_t)r * 128 + kf));
        }
#pragma unroll
        for (int t = 0; t < 8; ++t) {
            bf16x8 bhi = __builtin_bit_cast(bf16x8, *(const us8*)(&sHi[(t * 16 + lc) * 136 + kf]));
            bf16x8 blo = __builtin_bit_cast(bf16x8, *(const us8*)(&sLo[(t * 16 + lc) * 136 + kf]));
#pragma unroll
            for (int rs = 0; rs < 2; ++rs) {
                acc[rs][t] = __builtin_amdgcn_mfma_f32_16x16x32_bf16(a[rs], bhi, acc[rs][t], 0, 0, 0);
                acc[rs][t] = __builtin_amdgcn_mfma_f32_16x16x32_bf16(a[rs], blo, acc[rs][t], 0, 0, 0);
            }
        }
    }

    float av = (mode == 1) ? prelu_a[0] : 0.f;
#pragma unroll
    for (int t = 0; t < 8; ++t) {
        int gcol = t * 16 + lc;
        float bv = (mode != 0) ? bias[gcol] : 0.f;
#pragma unroll
        for (int rs = 0; rs < 2; ++rs) {
#pragma unroll
            for (int i = 0; i < 4; ++i) {
                int r = rowBlock + rs * 16 + quad * 4 + i;
                if (r < M) {
                    float v = acc[rs][t][i] + bv;
                    if (mode == 1) v = (v > 0.f) ? v : av * v;
                    if (mode == 2) Cf[(size_t)r * 128 + gcol] = v;
                    else           Cb[(size_t)r * 128 + gcol] = f2bf(v);
                }
            }
        }
    }
}

// ---------------- GCN aggregation: one 32-lane group per node ----------------
// out[n] = relu( dinv[n] * sum_e dinv[src_e]*h[src_e] + selfw[n]*h[n] + b )
// edge records are 4B (src); per-edge weight rebuilt from L2-resident dinv via
// broadcast loads; dinv[dst] factored out of the sum.
__global__ __launch_bounds__(256) void aggregate(
    const unsigned short* __restrict__ Hhi, const float* __restrict__ dinv,
    const float* __restrict__ selfw,
    const int* __restrict__ rowptr, const int* __restrict__ epack,
    const float* __restrict__ bias, float* __restrict__ outF,
    unsigned short* __restrict__ outHi, int N)
{
    const int tid = threadIdx.x;
    const int g = tid >> 5;
    const int l = tid & 31;
    const int n = blockIdx.x * 8 + g;
    if (n >= N) return;

    const int beg = rowptr[n], end = rowptr[n + 1];
    const size_t fo = (size_t)l * 4;           // this lane's 4-feature slot

    f32x4 a0 = {0.f, 0.f, 0.f, 0.f};
    f32x4 a1 = a0, a2 = a0, a3 = a0;

    int i = beg;
    for (; i + 3 < end; i += 4) {
        int s0 = epack[i];
        int s1 = epack[i + 1];
        int s2 = epack[i + 2];
        int s3 = epack[i + 3];
        us4 h0 = *(const us4*)(Hhi + (size_t)s0 * 128 + fo);
        us4 h1 = *(const us4*)(Hhi + (size_t)s1 * 128 + fo);
        us4 h2 = *(const us4*)(Hhi + (size_t)s2 * 128 + fo);
        us4 h3 = *(const us4*)(Hhi + (size_t)s3 * 128 + fo);
        float w0 = dinv[s0];
        float w1 = dinv[s1];
        float w2 = dinv[s2];
        float w3 = dinv[s3];
#pragma unroll
        for (int j = 0; j < 4; ++j) a0[j] += w0 * bf2f(h0[j]);
#pragma unroll
        for (int j = 0; j < 4; ++j) a1[j] += w1 * bf2f(h1[j]);
#pragma unroll
        for (int j = 0; j < 4; ++j) a2[j] += w2 * bf2f(h2[j]);
#pragma unroll
        for (int j = 0; j < 4; ++j) a3[j] += w3 * bf2f(h3[j]);
    }
    for (; i < end; ++i) {
        int s0 = epack[i];
        us4 h0 = *(const us4*)(Hhi + (size_t)s0 * 128 + fo);
        float w0 = dinv[s0];
#pragma unroll
        for (int j = 0; j < 4; ++j) a0[j] += w0 * bf2f(h0[j]);
    }

    // self + bias + relu
    float dn = dinv[n];
    float sw = selfw[n];
    us4 sh = *(const us4*)(Hhi + (size_t)n * 128 + fo);
    f32x4 b4 = *(const f32x4*)(bias + l * 4);
    f32x4 sum = (a0 + a1) + (a2 + a3);
    f32x4 v;
    us4 ob;
#pragma unroll
    for (int j = 0; j < 4; ++j) {
        v[j] = fmaxf(dn * sum[j] + sw * bf2f(sh[j]) + b4[j], 0.f);
        ob[j] = f2bf(v[j]);
    }
    if (outF) *(f32x4*)(outF + (size_t)n * 128 + fo) = v;
    *(us4*)(outHi + (size_t)n * 128 + fo) = ob;
}

// ---------------- launch ----------------
extern "C" void kernel_launch(void* const* d_in, const int* in_sizes, int n_in,
                              void* d_out, int out_size, void* d_ws, size_t ws_size,
                              hipStream_t stream)
{
    const float* x   = (const float*)d_in[0];
    const int*   ei  = (const int*)d_in[1];
    const float* W1  = (const float*)d_in[2];
    const float* b1  = (const float*)d_in[3];
    const float* W2  = (const float*)d_in[4];
    const float* b2  = (const float*)d_in[5];
    const float* Wp1 = (const float*)d_in[6];
    const float* bp1 = (const float*)d_in[7];
    const float* pa  = (const float*)d_in[8];
    const float* Wp2 = (const float*)d_in[9];
    const float* bp2 = (const float*)d_in[10];

    const int N = in_sizes[0] / 128;
    const int E = in_sizes[1] / 2;
    const int* src = ei;
    const int* dst = ei + E;

    float* outF = (float*)d_out;
    float* zbuf = outF;                        // output 0: z
    float* pbuf = outF + (size_t)N * 128;      // output 1: p

    char* w = (char*)d_ws;
    size_t off = 0;
    auto alloc = [&](size_t bytes) {
        void* p = w + off;
        off = (off + bytes + 255) & ~(size_t)255;
        return p;
    };
    unsigned short* S1 = (unsigned short*)alloc((size_t)N * 128 * sizeof(unsigned short));
    unsigned short* S2 = (unsigned short*)alloc((size_t)N * 128 * sizeof(unsigned short));
    float* dinv   = (float*)alloc((size_t)N * sizeof(float));
    float* selfw  = (float*)alloc((size_t)N * sizeof(float));
    int*   rowptr = (int*)alloc((size_t)(N + 1) * sizeof(int));
    int*   cntcur = (int*)alloc((size_t)N * sizeof(int));
    int*   epack  = (int*)alloc((size_t)E * sizeof(int));
    int*   bsum   = (int*)alloc(1024);
    unsigned short* wt = (unsigned short*)alloc((size_t)4 * 2 * 128 * 128 * sizeof(unsigned short));
    (void)ws_size; (void)n_in; (void)out_size;

    auto hiP = [&](int m) { return wt + (size_t)m * 32768; };
    auto loP = [&](int m) { return wt + (size_t)m * 32768 + 16384; };

    // weight conversion (fused) + x -> bf16
    hipLaunchKernelGGL(prep_w4, dim3(256), dim3(256), 0, stream, W1, W2, Wp1, Wp2, wt);
    const int n4 = N * 128 / 4;
    hipLaunchKernelGGL(to_bf16, dim3((n4 + 255) / 256), dim3(256), 0, stream, x, S1, n4);

    // CSR by dst + per-edge records
    hipMemsetAsync(cntcur, 0, (size_t)N * sizeof(int), stream);
    const int nb = (N + 1023) >> 10;
    hipLaunchKernelGGL(count_deg, dim3((E + 255) / 256), dim3(256), 0, stream, dst, cntcur, E);
    hipLaunchKernelGGL(scanA,     dim3(nb), dim3(1024), 0, stream, cntcur, rowptr, bsum, N);
    hipLaunchKernelGGL(scanB,     dim3(1), dim3(128), 0, stream, bsum, nb);
    hipLaunchKernelGGL(scanC,     dim3((N + 255) / 256), dim3(256), 0, stream, rowptr, bsum, cntcur, dinv, selfw, N, E);
    // 8 dst-range passes: blockIdx&7 = range, so each range's scattered writes
    // stay on one XCD's L2 and merge into full lines before writeback.
    hipLaunchKernelGGL(fill_csr,  dim3(8 * ((E + 255) / 256)), dim3(256), 0, stream,
                       src, dst, cntcur, epack, E, N);

    const int gb = (N + 127) / 128;
    const int ab = (N + 7) / 8;
    // conv1: h1 = x@W1 -> S2 ; z1 = relu(agg(h1)+b1) -> S1
    hipLaunchKernelGGL(gemm128s, dim3(gb), dim3(256), 0, stream, S1, hiP(0), loP(0),
                       (const float*)nullptr, (const float*)nullptr, (float*)nullptr, S2, N, 0);
    hipLaunchKernelGGL(aggregate, dim3(ab), dim3(256), 0, stream, S2, dinv, selfw, rowptr, epack,
                       b1, (float*)nullptr, S1, N);
    // conv2: h2 = z1@W2 -> S2 ; z = relu(agg(h2)+b2) -> zbuf(f32) + S1(bf16)
    hipLaunchKernelGGL(gemm128s, dim3(gb), dim3(256), 0, stream, S1, hiP(1), loP(1),
                       (const float*)nullptr, (const float*)nullptr, (float*)nullptr, S2, N, 0);
    hipLaunchKernelGGL(aggregate, dim3(ab), dim3(256), 0, stream, S2, dinv, selfw, rowptr, epack,
                       b2, zbuf, S1, N);
    // projection: h = prelu(z@Wp1+bp1) -> S2 ; p = h@Wp2+bp2 -> pbuf(f32)
    hipLaunchKernelGGL(gemm128s, dim3(gb), dim3(256), 0, stream, S1, hiP(2), loP(2),
                       bp1, pa, (float*)nullptr, S2, N, 1);
    hipLaunchKernelGGL(gemm128s, dim3(gb), dim3(256), 0, stream, S2, hiP(3), loP(3),
                       bp2, (const float*)nullptr, pbuf, (unsigned short*)nullptr, N, 2);
}